// Round 27
// baseline (205.046 us; speedup 1.0000x reference)
//
#include <hip/hip_runtime.h>
#include <hip/hip_bf16.h>

// VQ-VAE forward, B=64, F=16.  d_out = float*: decoded 4194304 f32, indices 262144 f32.  ws = 256 MiB.
// R27: er2->vq handoff in hi/lo bf16 NCHW planes (was fp32 NCHW): link traffic 134->67MB. vq argmin
//      over hi+lo (same ~2^-18 perturbation class as R20/R24 split-MFMA inputs, both index-exact).
//      All else byte-identical to R26 (202.3us). Pre-commit: Output1 fails -> revert link to fp32.
// Lessons: uniform weights->SGPR (R10); matrix pipe beats scalar wall (R17/R20); hoist frag builds
//      (R22); merge parity classes (R23); split-bf16 Dekker index-exact (R20/R24); at <25us/kernel
//      only traffic elimination pays (R26).

#define R8X(M)  M(0) M(1) M(2) M(3) M(4) M(5) M(6) M(7)

typedef __attribute__((ext_vector_type(8))) short          bf16x8;
typedef __attribute__((ext_vector_type(8))) unsigned short u16x8;
typedef __attribute__((ext_vector_type(4))) float          f32x4;

__device__ __forceinline__ unsigned short f2bf(float f) {   // RNE fp32 -> bf16 bits
    unsigned u; __builtin_memcpy(&u, &f, 4);
    unsigned r = u + 0x7FFFu + ((u >> 16) & 1u);
    return (unsigned short)(r >> 16);
}
__device__ __forceinline__ float bf2f(unsigned short h) {
    unsigned u = ((unsigned)h) << 16;
    float f; __builtin_memcpy(&f, &u, 4);
    return f;
}

// ---------------- conv1: 1->16, 256->128 — hi/lo bf16, PARITY-PLANE ch-last ----------------
__global__ __launch_bounds__(256) void conv1_k(const float* __restrict__ x, const float* __restrict__ w,
                                               const float* __restrict__ bias,
                                               unsigned short* __restrict__ oh, unsigned short* __restrict__ ol) {
    int idx = blockIdx.x * 256 + threadIdx.x;   // 64*128*128
    int ox = idx & 127;
    int oy = (idx >> 7) & 127;
    int b  = idx >> 14;
    const float* xin = x + (size_t)b * 65536;
    float pv[16];
#pragma unroll
    for (int ky = 0; ky < 4; ++ky) {
        int iy = 2 * oy - 1 + ky;
#pragma unroll
        for (int kx = 0; kx < 4; ++kx) {
            int ix = 2 * ox - 1 + kx;
            pv[ky * 4 + kx] = (iy >= 0 && iy < 256 && ix >= 0 && ix < 256)
                                  ? xin[iy * 256 + ix] : 0.f;
        }
    }
    u16x8 h0, h1, l0, l1;
#pragma unroll
    for (int oc = 0; oc < 16; ++oc) {
        float acc = bias[oc];
#pragma unroll
        for (int k = 0; k < 16; ++k) acc = fmaf(pv[k], w[oc * 16 + k], acc);
        float r = fmaxf(acc, 0.f);
        unsigned short hb = f2bf(r);
        unsigned short lb = f2bf(r - bf2f(hb));
        if (oc < 8) { h0[oc] = hb; l0[oc] = lb; }
        else        { h1[oc - 8] = hb; l1[oc - 8] = lb; }
    }
    int p = ((oy & 1) << 1) | (ox & 1);
    size_t base = ((((size_t)p * 64 + b) * 4096) + (size_t)(oy >> 1) * 64 + (ox >> 1)) * 16;
    u16x8* po = (u16x8*)(oh + base);
    po[0] = h0; po[1] = h1;
    u16x8* pl = (u16x8*)(ol + base);
    pl[0] = l0; pl[1] = l1;
}

// ---------------- conv2 via split-bf16 MFMA: K=256, 3 chains — parity-plane dense reads ----------------
__global__ __launch_bounds__(256) void conv2_mfma_k(const unsigned short* __restrict__ fh,
                                                    const unsigned short* __restrict__ fl,
                                                    const float* __restrict__ w, const float* __restrict__ bias,
                                                    unsigned short* __restrict__ oh, unsigned short* __restrict__ ol) {
    __shared__ unsigned short wsh[16 * 264];
    __shared__ unsigned short wsl[16 * 264];
    for (int i = threadIdx.x; i < 4096; i += 256) {
        int oc = i >> 8, k = i & 255;
        int ic = k & 15, tap = k >> 4;
        float f = w[oc * 256 + ic * 16 + tap];
        unsigned short hb = f2bf(f);
        wsh[oc * 264 + k] = hb;
        wsl[oc * 264 + k] = f2bf(f - bf2f(hb));
    }
    __syncthreads();

    int wid  = threadIdx.x >> 6;
    int lane = threadIdx.x & 63;
    int col = lane & 15;
    int kg  = lane >> 4;
    int ic0 = (kg & 1) * 8;
    float accb = bias[col];
    int gw = blockIdx.x * 4 + wid;

    for (int t = 0; t < 2; ++t) {
        int tile = gw * 2 + t;
        int v0  = (tile & 3) * 16;
        int y   = (tile >> 2) & 63;
        int img = tile >> 8;
        f32x4 acc = { accb, accb, accb, accb };
#pragma unroll
        for (int m = 0; m < 8; ++m) {
            int tap = 2 * m + (kg >> 1);
            int ty = tap >> 2, tx = tap & 3;
            int py = (ty + 1) & 1, px = (tx + 1) & 1;      // parity plane
            int y2 = y + ((ty - 1) >> 1);
            int x2 = v0 + col + ((tx - 1) >> 1);
            bf16x8 ah = { 0, 0, 0, 0, 0, 0, 0, 0 };
            bf16x8 al = { 0, 0, 0, 0, 0, 0, 0, 0 };
            if (y2 >= 0 && y2 < 64 && x2 >= 0 && x2 < 64) {
                size_t off = ((((size_t)(py * 2 + px) * 64 + img) * 4096) + (size_t)y2 * 64 + x2) * 16 + ic0;
                ah = *(const bf16x8*)(fh + off);
                al = *(const bf16x8*)(fl + off);
            }
            bf16x8 wh = *(const bf16x8*)&wsh[col * 264 + m * 32 + kg * 8];
            bf16x8 wl = *(const bf16x8*)&wsl[col * 264 + m * 32 + kg * 8];
            acc = __builtin_amdgcn_mfma_f32_16x16x32_bf16(ah, wh, acc, 0, 0, 0);
            acc = __builtin_amdgcn_mfma_f32_16x16x32_bf16(al, wh, acc, 0, 0, 0);
            acc = __builtin_amdgcn_mfma_f32_16x16x32_bf16(ah, wl, acc, 0, 0, 0);
        }
#pragma unroll
        for (int r = 0; r < 4; ++r) {
            int xx = v0 + kg * 4 + r;
            size_t ad = (size_t)img * 65536 + ((size_t)(y * 64 + xx)) * 16 + col;   // ch-last
            float rv = fmaxf(acc[r], 0.f);
            unsigned short hb = f2bf(rv);
            oh[ad] = hb;
            ol[ad] = f2bf(rv - bf2f(hb));
        }
    }
}

// ---------------- er res via split-bf16 MFMA: K=144 pad 176 ----------------
// OUTMODE 0: hi/lo ch-last. OUTMODE 1: hi/lo bf16 NCHW planes (vq handoff).
template <int OUTMODE>
__global__ __launch_bounds__(256) void er_mfma_k(const unsigned short* __restrict__ inh,
                                                 const unsigned short* __restrict__ inl,
                                                 const float* __restrict__ w, const float* __restrict__ bias,
                                                 unsigned short* __restrict__ oh, unsigned short* __restrict__ ol) {
    __shared__ unsigned short wsh[16 * 176];
    __shared__ unsigned short wsl[16 * 176];
    for (int i = threadIdx.x; i < 2816; i += 256) {
        int oc = i / 176, k = i % 176;
        float f = (k < 144) ? w[(oc * 16 + (k & 15)) * 9 + (k >> 4)] : 0.f;
        unsigned short hb = f2bf(f);
        wsh[i] = hb;
        wsl[i] = f2bf(f - bf2f(hb));
    }
    __syncthreads();

    int wid  = threadIdx.x >> 6;
    int lane = threadIdx.x & 63;
    int col = lane & 15;
    int kg  = lane >> 4;
    int ic0 = (kg & 1) * 8;
    float accb = bias[col];
    int gw = blockIdx.x * 4 + wid;       // 4096 waves x 4 tiles

    for (int t = 0; t < 4; ++t) {
        int tile = gw * 4 + t;
        int v0  = (tile & 3) * 16;
        int y   = (tile >> 2) & 63;
        int img = tile >> 8;
        const unsigned short* xh = inh + (size_t)img * 65536;
        const unsigned short* xl = inl + (size_t)img * 65536;
        f32x4 acc = { accb, accb, accb, accb };
#pragma unroll
        for (int m = 0; m < 5; ++m) {
            int tap = 2 * m + (kg >> 1);     // 0..9, tap 9 = zero pad
            bf16x8 ah = { 0, 0, 0, 0, 0, 0, 0, 0 };
            bf16x8 al = { 0, 0, 0, 0, 0, 0, 0, 0 };
            if (tap < 9) {
                int ty = tap / 3, tx = tap - ty * 3;
                int jy = y + ty - 1;
                int jx = v0 + col + tx - 1;
                if (jy >= 0 && jy < 64 && jx >= 0 && jx < 64) {
                    size_t off = ((size_t)(jy * 64 + jx)) * 16 + ic0;
                    ah = *(const bf16x8*)(xh + off);
                    al = *(const bf16x8*)(xl + off);
                }
            }
            bf16x8 wh = *(const bf16x8*)&wsh[col * 176 + m * 32 + kg * 8];
            bf16x8 wl = *(const bf16x8*)&wsl[col * 176 + m * 32 + kg * 8];
            acc = __builtin_amdgcn_mfma_f32_16x16x32_bf16(ah, wh, acc, 0, 0, 0);
            acc = __builtin_amdgcn_mfma_f32_16x16x32_bf16(al, wh, acc, 0, 0, 0);
            acc = __builtin_amdgcn_mfma_f32_16x16x32_bf16(ah, wl, acc, 0, 0, 0);
        }
#pragma unroll
        for (int r = 0; r < 4; ++r) {
            int px = v0 + kg * 4 + r;
            size_t ad = ((size_t)(y * 64 + px)) * 16 + col;
            float vin = bf2f(xh[ad]) + bf2f(xl[ad]);
            float res = vin + fmaxf(acc[r], 0.f);
            unsigned short hb = f2bf(res);
            unsigned short lb = f2bf(res - bf2f(hb));
            if (OUTMODE == 0) {
                oh[(size_t)img * 65536 + ad] = hb;       // ch-last
                ol[(size_t)img * 65536 + ad] = lb;
            } else {
                size_t an = (size_t)img * 65536 + (size_t)col * 4096 + y * 64 + px;   // NCHW
                oh[an] = hb;
                ol[an] = lb;
            }
        }
    }
}

// ---------------- VQ fused with transpose: hi/lo bf16 NCHW input; ch-last bf16 q out ----------------
__global__ __launch_bounds__(256) void vq_k(const unsigned short* __restrict__ hh,
                                            const unsigned short* __restrict__ hl,
                                            const float* __restrict__ cb,
                                            unsigned short* __restrict__ qc, float* __restrict__ idx_out) {
    __shared__ float cbs[1024];  // 64 x 16
    __shared__ float cn[64];
    __shared__ unsigned short st[4096];  // [yl][x][c]
    for (int i = threadIdx.x; i < 1024; i += 256) cbs[i] = cb[i];
    __syncthreads();
    if (threadIdx.x < 64) {
        float s = 0.f;
#pragma unroll
        for (int d = 0; d < 16; ++d) { float v = cbs[threadIdx.x * 16 + d]; s = fmaf(v, v, s); }
        cn[threadIdx.x] = s;
    }
    __syncthreads();

    int blk = blockIdx.x;                // 1024 = 64 img x 16 bands
    int b  = blk >> 4;
    int y0 = (blk & 15) * 4;
    int t  = threadIdx.x;
    int c  = t >> 4;
    int yl = (t >> 2) & 3;
    int xc = t & 3;
    int r  = b * 4096 + c * 256 + (y0 + yl) * 4 + xc;   // raw-flatten row id

    float f[16];
    const u16x8* hp = (const u16x8*)(hh + (size_t)r * 16);
    const u16x8* lp = (const u16x8*)(hl + (size_t)r * 16);
    u16x8 vh0 = hp[0], vh1 = hp[1];
    u16x8 vl0 = lp[0], vl1 = lp[1];
#pragma unroll
    for (int j = 0; j < 8; ++j) {
        f[j]     = bf2f(vh0[j]) + bf2f(vl0[j]);
        f[j + 8] = bf2f(vh1[j]) + bf2f(vl1[j]);
    }
    float best = 3.4e38f;
    int bi = 0;
    for (int k = 0; k < 64; ++k) {
        float dot = 0.f;
#pragma unroll
        for (int d = 0; d < 16; ++d) dot = fmaf(f[d], cbs[k * 16 + d], dot);
        float dist = cn[k] - 2.f * dot;
        if (dist < best) { best = dist; bi = k; }
    }
    idx_out[r] = (float)bi;

#pragma unroll
    for (int j = 0; j < 16; ++j)
        st[((yl * 64) + (xc * 16 + j)) * 16 + c] = f2bf(cbs[bi * 16 + j]);
    __syncthreads();

    u16x8* dst = (u16x8*)(qc + (((size_t)(b * 64 + y0)) * 64) * 16);
    const u16x8* src = (const u16x8*)st;
#pragma unroll
    for (int i = 0; i < 2; ++i)
        dst[t + 256 * i] = src[t + 256 * i];
}

// ---------------- res via plain bf16 MFMA (decoder): 1024 blocks x 4 tiles ----------------
__global__ __launch_bounds__(256) void res_mfma_k(const unsigned short* __restrict__ in,
                                                  const float* __restrict__ w, const float* __restrict__ bias,
                                                  unsigned short* __restrict__ outb) {
    int wid  = threadIdx.x >> 6;
    int lane = threadIdx.x & 63;
    int col = lane & 15;
    int kg  = lane >> 4;
    int ic0 = (kg & 1) * 8;

    bf16x8 bw[5];
#pragma unroll
    for (int m = 0; m < 5; ++m) {
        int tap = 2 * m + (kg >> 1);
        bf16x8 t = { 0, 0, 0, 0, 0, 0, 0, 0 };
        if (tap < 9) {
#pragma unroll
            for (int j = 0; j < 8; ++j)
                t[j] = (short)f2bf(w[(col * 16 + ic0 + j) * 9 + tap]);
        }
        bw[m] = t;
    }
    float accb = bias[col];

    int gw = blockIdx.x * 4 + wid;       // 4096 waves x 4 tiles
    for (int t = 0; t < 4; ++t) {
        int tile = gw * 4 + t;
        int v0  = (tile & 3) * 16;
        int y   = (tile >> 2) & 63;
        int img = tile >> 8;
        const unsigned short* xi = in + (size_t)img * 65536;
        f32x4 acc = { accb, accb, accb, accb };
#pragma unroll
        for (int m = 0; m < 5; ++m) {
            int tap = 2 * m + (kg >> 1);
            bf16x8 a = { 0, 0, 0, 0, 0, 0, 0, 0 };
            if (tap < 9) {
                int ty = tap / 3, tx = tap - ty * 3;
                int jy = y + ty - 1;
                int jx = v0 + col + tx - 1;
                if (jy >= 0 && jy < 64 && jx >= 0 && jx < 64)
                    a = *(const bf16x8*)(xi + ((jy * 64 + jx) * 16 + ic0));
            }
            acc = __builtin_amdgcn_mfma_f32_16x16x32_bf16(a, bw[m], acc, 0, 0, 0);
        }
#pragma unroll
        for (int r = 0; r < 4; ++r) {
            int px = v0 + kg * 4 + r;
            size_t ad = (size_t)(y * 64 + px) * 16 + col;
            float vin = bf2f(xi[ad]);
            outb[(size_t)img * 65536 + ad] = f2bf(vin + fmaxf(acc[r], 0.f));
        }
    }
}

// ---------------- tconv1 via MFMA: per parity class GEMM — bf16 out ----------------
__global__ __launch_bounds__(256) void tconv1_mfma_k(const unsigned short* __restrict__ xb,
                                                     const float* __restrict__ w1, const float* __restrict__ bia,
                                                     unsigned short* __restrict__ outb) {
    int cls = blockIdx.x >> 9;           // 4 classes x 512 blocks
    int bb  = blockIdx.x & 511;
    int DY = cls >> 1, DX = cls & 1;
    int wid  = threadIdx.x >> 6;
    int lane = threadIdx.x & 63;
    int oc = lane & 15;
    int kg = lane >> 4;

    bf16x8 bfr0, bfr1;
    float accb = bia[oc];
#pragma unroll
    for (int m = 0; m < 2; ++m) {
        int tap = 2 * m + (kg >> 1);
        int ty = tap >> 1, tx = tap & 1;
        int koff = (3 - DY - 2 * ty) * 4 + (3 - DX - 2 * tx);
        int ic0 = (kg & 1) * 8;
        bf16x8 t;
#pragma unroll
        for (int j = 0; j < 8; ++j)
            t[j] = (short)f2bf(w1[(ic0 + j) * 256 + oc * 16 + koff]);
        if (m == 0) bfr0 = t; else bfr1 = t;
    }

    int Wc = bb * 4 + wid;
    for (int t = 0; t < 8; ++t) {
        int tile = Wc * 8 + t;
        int v0  = (tile & 3) * 16;
        int u   = (tile >> 2) & 63;
        int img = tile >> 8;
        const unsigned short* xi = xb + (size_t)img * 65536;
        f32x4 acc = { accb, accb, accb, accb };
#pragma unroll
        for (int m = 0; m < 2; ++m) {
            int tap = 2 * m + (kg >> 1);
            int ty = tap >> 1, tx = tap & 1;
            int jy = u + DY - 1 + ty;
            int jx = v0 + oc + DX - 1 + tx;
            bf16x8 a = { 0, 0, 0, 0, 0, 0, 0, 0 };
            if (jy >= 0 && jy < 64 && jx >= 0 && jx < 64) {
                int ic0 = (kg & 1) * 8;
                a = *(const bf16x8*)(xi + ((jy * 64 + jx) * 16 + ic0));
            }
            acc = __builtin_amdgcn_mfma_f32_16x16x32_bf16(a, (m == 0 ? bfr0 : bfr1), acc, 0, 0, 0);
        }
        int my = 2 * u + DY;
#pragma unroll
        for (int r = 0; r < 4; ++r) {
            int pxr = kg * 4 + r;
            int mx  = 2 * (v0 + pxr) + DX;
            outb[(((size_t)img * 16384) + my * 128 + mx) * 16 + oc] = f2bf(fmaxf(acc[r], 0.f));
        }
    }
}

// ---------------- tconv2: 2x2-quad kernel — 3x3 shared neighborhood, contiguous stores ----------------
template <int RY, int RX>
__device__ __forceinline__ void quad_contrib(const unsigned short* __restrict__ px,
                                             const float* __restrict__ w2,
                                             float& a00, float& a01, float& a10, float& a11) {
    constexpr int nY = (RY == 0) ? 2 : 1;
    constexpr int nX = (RX == 0) ? 2 : 1;
    constexpr int dyA[2] = { (RY == 1) ? 1 : 0, 1 };
    constexpr int kyA[2] = { (RY == -1) ? 3 : ((RY == 0) ? 1 : 0), 2 };
    constexpr int dxA[2] = { (RX == 1) ? 1 : 0, 1 };
    constexpr int kxA[2] = { (RX == -1) ? 3 : ((RX == 0) ? 1 : 0), 2 };
    u16x8 h0 = *(const u16x8*)px;
    u16x8 h1 = *(const u16x8*)(px + 8);
#pragma unroll
    for (int iy = 0; iy < nY; ++iy) {
#pragma unroll
        for (int ix = 0; ix < nX; ++ix) {
            const int ky = kyA[iy], kx = kxA[ix];
            float& a = (dyA[iy] == 0) ? ((dxA[ix] == 0) ? a00 : a01)
                                      : ((dxA[ix] == 0) ? a10 : a11);
#pragma unroll
            for (int ic = 0; ic < 8; ++ic)
                a = fmaf(bf2f(h0[ic]), w2[ic * 16 + ky * 4 + kx], a);
#pragma unroll
            for (int ic = 0; ic < 8; ++ic)
                a = fmaf(bf2f(h1[ic]), w2[(ic + 8) * 16 + ky * 4 + kx], a);
        }
    }
}

__global__ __launch_bounds__(256) void tconv2_quad_k(const unsigned short* __restrict__ f1b,
                                                     const float* __restrict__ w2, const float* __restrict__ b2,
                                                     float* __restrict__ out) {
    int idx = blockIdx.x * 256 + threadIdx.x;   // 64 img * 128*128 quads
    int v = idx & 127;
    int u = (idx >> 7) & 127;
    int b = idx >> 14;
    const unsigned short* fb = f1b + (size_t)b * 262144;
    float b2s = b2[0];
    float a00 = b2s, a01 = b2s, a10 = b2s, a11 = b2s;

#define QC(RY, RX) { int jy = u + (RY), jx = v + (RX); \
    if (jy >= 0 && jy < 128 && jx >= 0 && jx < 128) \
        quad_contrib<RY, RX>(fb + ((size_t)(jy * 128 + jx) << 4), w2, a00, a01, a10, a11); }
    QC(-1, -1) QC(-1, 0) QC(-1, 1)
    QC( 0, -1) QC( 0, 0) QC( 0, 1)
    QC( 1, -1) QC( 1, 0) QC( 1, 1)
#undef QC

    float* o = out + (size_t)b * 65536 + (2 * u) * 256 + 2 * v;
    float2 r0; r0.x = a00; r0.y = a01;
    float2 r1; r1.x = a10; r1.y = a11;
    *(float2*)o         = r0;
    *(float2*)(o + 256) = r1;
}

extern "C" void kernel_launch(void* const* d_in, const int* in_sizes, int n_in,
                              void* d_out, int out_size, void* d_ws, size_t ws_size,
                              hipStream_t stream) {
    const float* x    = (const float*)d_in[0];
    const float* c1w  = (const float*)d_in[1];
    const float* c1b  = (const float*)d_in[2];
    const float* c2w  = (const float*)d_in[3];
    const float* c2b  = (const float*)d_in[4];
    const float* er1w = (const float*)d_in[5];
    const float* er1b = (const float*)d_in[6];
    const float* er2w = (const float*)d_in[7];
    const float* er2b = (const float*)d_in[8];
    const float* cb   = (const float*)d_in[9];
    const float* dr1w = (const float*)d_in[10];
    const float* dr1b = (const float*)d_in[11];
    const float* dr2w = (const float*)d_in[12];
    const float* dr2b = (const float*)d_in[13];
    const float* t1w  = (const float*)d_in[14];
    const float* t1b  = (const float*)d_in[15];
    const float* t2w  = (const float*)d_in[16];
    const float* t2b  = (const float*)d_in[17];

    char* W = (char*)d_ws;                       // 256 MiB
    const size_t MB = 1024 * 1024;
    unsigned short* f1h = (unsigned short*)(W + 0);          // conv1 hi parity-plane, 32 MiB
    unsigned short* f1l = (unsigned short*)(W + 32 * MB);    // conv1 lo parity-plane
    unsigned short* c2h = (unsigned short*)(W + 64 * MB);    // conv2 hi (64,64,64,16) ch-last
    unsigned short* c2l = (unsigned short*)(W + 80 * MB);    // conv2 lo
    unsigned short* e1h = (unsigned short*)(W + 96 * MB);    // er1 hi ch-last
    unsigned short* e1l = (unsigned short*)(W + 112 * MB);   // er1 lo
    unsigned short* e2h = (unsigned short*)(W + 128 * MB);   // er2 hi NCHW bf16 (vq handoff)
    unsigned short* e2l = (unsigned short*)(W + 140 * MB);   // er2 lo NCHW bf16
    unsigned short* qc  = (unsigned short*)(W + 152 * MB);   // quantized bf16 ch-last
    unsigned short* d1o = (unsigned short*)(W + 168 * MB);   // dr1 out ch-last bf16
    unsigned short* d2o = (unsigned short*)(W + 184 * MB);   // dr2 out ch-last bf16
    unsigned short* t1o = (unsigned short*)(W + 200 * MB);   // tconv1 out (64,128,128,16) bf16

    float* out     = (float*)d_out;
    float* idx_out = out + 4194304;

    conv1_k      <<<4096, 256, 0, stream>>>(x, c1w, c1b, f1h, f1l);
    conv2_mfma_k <<<2048, 256, 0, stream>>>(f1h, f1l, c2w, c2b, c2h, c2l);
    er_mfma_k<0> <<<1024, 256, 0, stream>>>(c2h, c2l, er1w, er1b, e1h, e1l);   // er1 (ch-last hi/lo)
    er_mfma_k<1> <<<1024, 256, 0, stream>>>(e1h, e1l, er2w, er2b, e2h, e2l);   // er2 (NCHW hi/lo)
    vq_k         <<<1024, 256, 0, stream>>>(e2h, e2l, cb, qc, idx_out);        // argmin on hi+lo
    res_mfma_k   <<<1024, 256, 0, stream>>>(qc, dr1w, dr1b, d1o);              // dr1 (bf16 MFMA)
    res_mfma_k   <<<1024, 256, 0, stream>>>(d1o, dr2w, dr2b, d2o);             // dr2 (bf16 MFMA)
    tconv1_mfma_k<<<2048, 256, 0, stream>>>(d2o, t1w, t1b, t1o);
    tconv2_quad_k<<<4096, 256, 0, stream>>>(t1o, t2w, t2b, out);
}

// Round 28
// 201.806 us; speedup vs baseline: 1.0161x; 1.0161x over previous
//
#include <hip/hip_runtime.h>
#include <hip/hip_bf16.h>

// VQ-VAE forward, B=64, F=16.  d_out = float*: decoded 4194304 f32, indices 262144 f32.  ws = 256 MiB.
// R28 = revert to R26 (best measured: 202.3us). R27's bf16 vq-handoff was within-noise negative ->
//      er2->vq link back to fp32 NCHW. Pipeline: conv1(hi/lo parity-plane) -> conv2 split-MFMA ->
//      er1/er2 split-MFMA -> vq(fused transpose, exact argmin) -> dr1/dr2 bf16 MFMA -> tconv1 MFMA
//      -> tconv2 quad. 2154 -> 202us cumulative (10.6x).
// Lessons bank: uniform weights->SGPR (R10); matrix pipe beats scalar wall (R17/R20); hoist frag
//      builds (R22); merge parity classes (R23); split-bf16 Dekker index-exact (R20/R24); at
//      <25us/kernel only traffic elimination pays (R26); short kernels cap at ~4.5TB/s (R27).

#define R8X(M)  M(0) M(1) M(2) M(3) M(4) M(5) M(6) M(7)

typedef __attribute__((ext_vector_type(8))) short          bf16x8;
typedef __attribute__((ext_vector_type(8))) unsigned short u16x8;
typedef __attribute__((ext_vector_type(4))) float          f32x4;

__device__ __forceinline__ unsigned short f2bf(float f) {   // RNE fp32 -> bf16 bits
    unsigned u; __builtin_memcpy(&u, &f, 4);
    unsigned r = u + 0x7FFFu + ((u >> 16) & 1u);
    return (unsigned short)(r >> 16);
}
__device__ __forceinline__ float bf2f(unsigned short h) {
    unsigned u = ((unsigned)h) << 16;
    float f; __builtin_memcpy(&f, &u, 4);
    return f;
}

// ---------------- conv1: 1->16, 256->128 — hi/lo bf16, PARITY-PLANE ch-last ----------------
__global__ __launch_bounds__(256) void conv1_k(const float* __restrict__ x, const float* __restrict__ w,
                                               const float* __restrict__ bias,
                                               unsigned short* __restrict__ oh, unsigned short* __restrict__ ol) {
    int idx = blockIdx.x * 256 + threadIdx.x;   // 64*128*128
    int ox = idx & 127;
    int oy = (idx >> 7) & 127;
    int b  = idx >> 14;
    const float* xin = x + (size_t)b * 65536;
    float pv[16];
#pragma unroll
    for (int ky = 0; ky < 4; ++ky) {
        int iy = 2 * oy - 1 + ky;
#pragma unroll
        for (int kx = 0; kx < 4; ++kx) {
            int ix = 2 * ox - 1 + kx;
            pv[ky * 4 + kx] = (iy >= 0 && iy < 256 && ix >= 0 && ix < 256)
                                  ? xin[iy * 256 + ix] : 0.f;
        }
    }
    u16x8 h0, h1, l0, l1;
#pragma unroll
    for (int oc = 0; oc < 16; ++oc) {
        float acc = bias[oc];
#pragma unroll
        for (int k = 0; k < 16; ++k) acc = fmaf(pv[k], w[oc * 16 + k], acc);
        float r = fmaxf(acc, 0.f);
        unsigned short hb = f2bf(r);
        unsigned short lb = f2bf(r - bf2f(hb));
        if (oc < 8) { h0[oc] = hb; l0[oc] = lb; }
        else        { h1[oc - 8] = hb; l1[oc - 8] = lb; }
    }
    int p = ((oy & 1) << 1) | (ox & 1);
    size_t base = ((((size_t)p * 64 + b) * 4096) + (size_t)(oy >> 1) * 64 + (ox >> 1)) * 16;
    u16x8* po = (u16x8*)(oh + base);
    po[0] = h0; po[1] = h1;
    u16x8* pl = (u16x8*)(ol + base);
    pl[0] = l0; pl[1] = l1;
}

// ---------------- conv2 via split-bf16 MFMA: K=256, 3 chains — parity-plane dense reads ----------------
__global__ __launch_bounds__(256) void conv2_mfma_k(const unsigned short* __restrict__ fh,
                                                    const unsigned short* __restrict__ fl,
                                                    const float* __restrict__ w, const float* __restrict__ bias,
                                                    unsigned short* __restrict__ oh, unsigned short* __restrict__ ol) {
    __shared__ unsigned short wsh[16 * 264];
    __shared__ unsigned short wsl[16 * 264];
    for (int i = threadIdx.x; i < 4096; i += 256) {
        int oc = i >> 8, k = i & 255;
        int ic = k & 15, tap = k >> 4;
        float f = w[oc * 256 + ic * 16 + tap];
        unsigned short hb = f2bf(f);
        wsh[oc * 264 + k] = hb;
        wsl[oc * 264 + k] = f2bf(f - bf2f(hb));
    }
    __syncthreads();

    int wid  = threadIdx.x >> 6;
    int lane = threadIdx.x & 63;
    int col = lane & 15;
    int kg  = lane >> 4;
    int ic0 = (kg & 1) * 8;
    float accb = bias[col];
    int gw = blockIdx.x * 4 + wid;

    for (int t = 0; t < 2; ++t) {
        int tile = gw * 2 + t;
        int v0  = (tile & 3) * 16;
        int y   = (tile >> 2) & 63;
        int img = tile >> 8;
        f32x4 acc = { accb, accb, accb, accb };
#pragma unroll
        for (int m = 0; m < 8; ++m) {
            int tap = 2 * m + (kg >> 1);
            int ty = tap >> 2, tx = tap & 3;
            int py = (ty + 1) & 1, px = (tx + 1) & 1;      // parity plane
            int y2 = y + ((ty - 1) >> 1);
            int x2 = v0 + col + ((tx - 1) >> 1);
            bf16x8 ah = { 0, 0, 0, 0, 0, 0, 0, 0 };
            bf16x8 al = { 0, 0, 0, 0, 0, 0, 0, 0 };
            if (y2 >= 0 && y2 < 64 && x2 >= 0 && x2 < 64) {
                size_t off = ((((size_t)(py * 2 + px) * 64 + img) * 4096) + (size_t)y2 * 64 + x2) * 16 + ic0;
                ah = *(const bf16x8*)(fh + off);
                al = *(const bf16x8*)(fl + off);
            }
            bf16x8 wh = *(const bf16x8*)&wsh[col * 264 + m * 32 + kg * 8];
            bf16x8 wl = *(const bf16x8*)&wsl[col * 264 + m * 32 + kg * 8];
            acc = __builtin_amdgcn_mfma_f32_16x16x32_bf16(ah, wh, acc, 0, 0, 0);
            acc = __builtin_amdgcn_mfma_f32_16x16x32_bf16(al, wh, acc, 0, 0, 0);
            acc = __builtin_amdgcn_mfma_f32_16x16x32_bf16(ah, wl, acc, 0, 0, 0);
        }
#pragma unroll
        for (int r = 0; r < 4; ++r) {
            int xx = v0 + kg * 4 + r;
            size_t ad = (size_t)img * 65536 + ((size_t)(y * 64 + xx)) * 16 + col;   // ch-last
            float rv = fmaxf(acc[r], 0.f);
            unsigned short hb = f2bf(rv);
            oh[ad] = hb;
            ol[ad] = f2bf(rv - bf2f(hb));
        }
    }
}

// ---------------- er res via split-bf16 MFMA: K=144 pad 176 ----------------
// OUTMODE 0: hi/lo ch-last out. OUTMODE 1: fp32 NCHW out (VQ handoff).
template <int OUTMODE>
__global__ __launch_bounds__(256) void er_mfma_k(const unsigned short* __restrict__ inh,
                                                 const unsigned short* __restrict__ inl,
                                                 const float* __restrict__ w, const float* __restrict__ bias,
                                                 unsigned short* __restrict__ oh, unsigned short* __restrict__ ol,
                                                 float* __restrict__ ofp) {
    __shared__ unsigned short wsh[16 * 176];
    __shared__ unsigned short wsl[16 * 176];
    for (int i = threadIdx.x; i < 2816; i += 256) {
        int oc = i / 176, k = i % 176;
        float f = (k < 144) ? w[(oc * 16 + (k & 15)) * 9 + (k >> 4)] : 0.f;
        unsigned short hb = f2bf(f);
        wsh[i] = hb;
        wsl[i] = f2bf(f - bf2f(hb));
    }
    __syncthreads();

    int wid  = threadIdx.x >> 6;
    int lane = threadIdx.x & 63;
    int col = lane & 15;
    int kg  = lane >> 4;
    int ic0 = (kg & 1) * 8;
    float accb = bias[col];
    int gw = blockIdx.x * 4 + wid;       // 4096 waves x 4 tiles

    for (int t = 0; t < 4; ++t) {
        int tile = gw * 4 + t;
        int v0  = (tile & 3) * 16;
        int y   = (tile >> 2) & 63;
        int img = tile >> 8;
        const unsigned short* xh = inh + (size_t)img * 65536;
        const unsigned short* xl = inl + (size_t)img * 65536;
        f32x4 acc = { accb, accb, accb, accb };
#pragma unroll
        for (int m = 0; m < 5; ++m) {
            int tap = 2 * m + (kg >> 1);     // 0..9, tap 9 = zero pad
            bf16x8 ah = { 0, 0, 0, 0, 0, 0, 0, 0 };
            bf16x8 al = { 0, 0, 0, 0, 0, 0, 0, 0 };
            if (tap < 9) {
                int ty = tap / 3, tx = tap - ty * 3;
                int jy = y + ty - 1;
                int jx = v0 + col + tx - 1;
                if (jy >= 0 && jy < 64 && jx >= 0 && jx < 64) {
                    size_t off = ((size_t)(jy * 64 + jx)) * 16 + ic0;
                    ah = *(const bf16x8*)(xh + off);
                    al = *(const bf16x8*)(xl + off);
                }
            }
            bf16x8 wh = *(const bf16x8*)&wsh[col * 176 + m * 32 + kg * 8];
            bf16x8 wl = *(const bf16x8*)&wsl[col * 176 + m * 32 + kg * 8];
            acc = __builtin_amdgcn_mfma_f32_16x16x32_bf16(ah, wh, acc, 0, 0, 0);
            acc = __builtin_amdgcn_mfma_f32_16x16x32_bf16(al, wh, acc, 0, 0, 0);
            acc = __builtin_amdgcn_mfma_f32_16x16x32_bf16(ah, wl, acc, 0, 0, 0);
        }
#pragma unroll
        for (int r = 0; r < 4; ++r) {
            int px = v0 + kg * 4 + r;
            size_t ad = ((size_t)(y * 64 + px)) * 16 + col;
            float vin = bf2f(xh[ad]) + bf2f(xl[ad]);
            float res = vin + fmaxf(acc[r], 0.f);
            if (OUTMODE == 0) {
                unsigned short hb = f2bf(res);
                oh[(size_t)img * 65536 + ad] = hb;
                ol[(size_t)img * 65536 + ad] = f2bf(res - bf2f(hb));
            } else {
                ofp[(size_t)img * 65536 + (size_t)col * 4096 + y * 64 + px] = res;   // NCHW
            }
        }
    }
}

// ---------------- VQ fused with transpose: fp32 NCHW input; ch-last bf16 q out ----------------
__global__ __launch_bounds__(256) void vq_k(const float* __restrict__ h, const float* __restrict__ cb,
                                            unsigned short* __restrict__ qc, float* __restrict__ idx_out) {
    __shared__ float cbs[1024];  // 64 x 16
    __shared__ float cn[64];
    __shared__ unsigned short st[4096];  // [yl][x][c]
    for (int i = threadIdx.x; i < 1024; i += 256) cbs[i] = cb[i];
    __syncthreads();
    if (threadIdx.x < 64) {
        float s = 0.f;
#pragma unroll
        for (int d = 0; d < 16; ++d) { float v = cbs[threadIdx.x * 16 + d]; s = fmaf(v, v, s); }
        cn[threadIdx.x] = s;
    }
    __syncthreads();

    int blk = blockIdx.x;                // 1024 = 64 img x 16 bands
    int b  = blk >> 4;
    int y0 = (blk & 15) * 4;
    int t  = threadIdx.x;
    int c  = t >> 4;
    int yl = (t >> 2) & 3;
    int xc = t & 3;
    int r  = b * 4096 + c * 256 + (y0 + yl) * 4 + xc;   // raw-flatten row id

    float f[16];
    const float4* hp = (const float4*)(h + (size_t)r * 16);
#pragma unroll
    for (int j = 0; j < 4; ++j) {
        float4 v = hp[j];
        f[j * 4 + 0] = v.x; f[j * 4 + 1] = v.y; f[j * 4 + 2] = v.z; f[j * 4 + 3] = v.w;
    }
    float best = 3.4e38f;
    int bi = 0;
    for (int k = 0; k < 64; ++k) {
        float dot = 0.f;
#pragma unroll
        for (int d = 0; d < 16; ++d) dot = fmaf(f[d], cbs[k * 16 + d], dot);
        float dist = cn[k] - 2.f * dot;
        if (dist < best) { best = dist; bi = k; }
    }
    idx_out[r] = (float)bi;

#pragma unroll
    for (int j = 0; j < 16; ++j)
        st[((yl * 64) + (xc * 16 + j)) * 16 + c] = f2bf(cbs[bi * 16 + j]);
    __syncthreads();

    u16x8* dst = (u16x8*)(qc + (((size_t)(b * 64 + y0)) * 64) * 16);
    const u16x8* src = (const u16x8*)st;
#pragma unroll
    for (int i = 0; i < 2; ++i)
        dst[t + 256 * i] = src[t + 256 * i];
}

// ---------------- res via plain bf16 MFMA (decoder): 1024 blocks x 4 tiles ----------------
__global__ __launch_bounds__(256) void res_mfma_k(const unsigned short* __restrict__ in,
                                                  const float* __restrict__ w, const float* __restrict__ bias,
                                                  unsigned short* __restrict__ outb) {
    int wid  = threadIdx.x >> 6;
    int lane = threadIdx.x & 63;
    int col = lane & 15;
    int kg  = lane >> 4;
    int ic0 = (kg & 1) * 8;

    bf16x8 bw[5];
#pragma unroll
    for (int m = 0; m < 5; ++m) {
        int tap = 2 * m + (kg >> 1);
        bf16x8 t = { 0, 0, 0, 0, 0, 0, 0, 0 };
        if (tap < 9) {
#pragma unroll
            for (int j = 0; j < 8; ++j)
                t[j] = (short)f2bf(w[(col * 16 + ic0 + j) * 9 + tap]);
        }
        bw[m] = t;
    }
    float accb = bias[col];

    int gw = blockIdx.x * 4 + wid;       // 4096 waves x 4 tiles
    for (int t = 0; t < 4; ++t) {
        int tile = gw * 4 + t;
        int v0  = (tile & 3) * 16;
        int y   = (tile >> 2) & 63;
        int img = tile >> 8;
        const unsigned short* xi = in + (size_t)img * 65536;
        f32x4 acc = { accb, accb, accb, accb };
#pragma unroll
        for (int m = 0; m < 5; ++m) {
            int tap = 2 * m + (kg >> 1);
            bf16x8 a = { 0, 0, 0, 0, 0, 0, 0, 0 };
            if (tap < 9) {
                int ty = tap / 3, tx = tap - ty * 3;
                int jy = y + ty - 1;
                int jx = v0 + col + tx - 1;
                if (jy >= 0 && jy < 64 && jx >= 0 && jx < 64)
                    a = *(const bf16x8*)(xi + ((jy * 64 + jx) * 16 + ic0));
            }
            acc = __builtin_amdgcn_mfma_f32_16x16x32_bf16(a, bw[m], acc, 0, 0, 0);
        }
#pragma unroll
        for (int r = 0; r < 4; ++r) {
            int px = v0 + kg * 4 + r;
            size_t ad = (size_t)(y * 64 + px) * 16 + col;
            float vin = bf2f(xi[ad]);
            outb[(size_t)img * 65536 + ad] = f2bf(vin + fmaxf(acc[r], 0.f));
        }
    }
}

// ---------------- tconv1 via MFMA: per parity class GEMM — bf16 out ----------------
__global__ __launch_bounds__(256) void tconv1_mfma_k(const unsigned short* __restrict__ xb,
                                                     const float* __restrict__ w1, const float* __restrict__ bia,
                                                     unsigned short* __restrict__ outb) {
    int cls = blockIdx.x >> 9;           // 4 classes x 512 blocks
    int bb  = blockIdx.x & 511;
    int DY = cls >> 1, DX = cls & 1;
    int wid  = threadIdx.x >> 6;
    int lane = threadIdx.x & 63;
    int oc = lane & 15;
    int kg = lane >> 4;

    bf16x8 bfr0, bfr1;
    float accb = bia[oc];
#pragma unroll
    for (int m = 0; m < 2; ++m) {
        int tap = 2 * m + (kg >> 1);
        int ty = tap >> 1, tx = tap & 1;
        int koff = (3 - DY - 2 * ty) * 4 + (3 - DX - 2 * tx);
        int ic0 = (kg & 1) * 8;
        bf16x8 t;
#pragma unroll
        for (int j = 0; j < 8; ++j)
            t[j] = (short)f2bf(w1[(ic0 + j) * 256 + oc * 16 + koff]);
        if (m == 0) bfr0 = t; else bfr1 = t;
    }

    int Wc = bb * 4 + wid;
    for (int t = 0; t < 8; ++t) {
        int tile = Wc * 8 + t;
        int v0  = (tile & 3) * 16;
        int u   = (tile >> 2) & 63;
        int img = tile >> 8;
        const unsigned short* xi = xb + (size_t)img * 65536;
        f32x4 acc = { accb, accb, accb, accb };
#pragma unroll
        for (int m = 0; m < 2; ++m) {
            int tap = 2 * m + (kg >> 1);
            int ty = tap >> 1, tx = tap & 1;
            int jy = u + DY - 1 + ty;
            int jx = v0 + oc + DX - 1 + tx;
            bf16x8 a = { 0, 0, 0, 0, 0, 0, 0, 0 };
            if (jy >= 0 && jy < 64 && jx >= 0 && jx < 64) {
                int ic0 = (kg & 1) * 8;
                a = *(const bf16x8*)(xi + ((jy * 64 + jx) * 16 + ic0));
            }
            acc = __builtin_amdgcn_mfma_f32_16x16x32_bf16(a, (m == 0 ? bfr0 : bfr1), acc, 0, 0, 0);
        }
        int my = 2 * u + DY;
#pragma unroll
        for (int r = 0; r < 4; ++r) {
            int pxr = kg * 4 + r;
            int mx  = 2 * (v0 + pxr) + DX;
            outb[(((size_t)img * 16384) + my * 128 + mx) * 16 + oc] = f2bf(fmaxf(acc[r], 0.f));
        }
    }
}

// ---------------- tconv2: 2x2-quad kernel — 3x3 shared neighborhood, contiguous stores ----------------
template <int RY, int RX>
__device__ __forceinline__ void quad_contrib(const unsigned short* __restrict__ px,
                                             const float* __restrict__ w2,
                                             float& a00, float& a01, float& a10, float& a11) {
    constexpr int nY = (RY == 0) ? 2 : 1;
    constexpr int nX = (RX == 0) ? 2 : 1;
    constexpr int dyA[2] = { (RY == 1) ? 1 : 0, 1 };
    constexpr int kyA[2] = { (RY == -1) ? 3 : ((RY == 0) ? 1 : 0), 2 };
    constexpr int dxA[2] = { (RX == 1) ? 1 : 0, 1 };
    constexpr int kxA[2] = { (RX == -1) ? 3 : ((RX == 0) ? 1 : 0), 2 };
    u16x8 h0 = *(const u16x8*)px;
    u16x8 h1 = *(const u16x8*)(px + 8);
#pragma unroll
    for (int iy = 0; iy < nY; ++iy) {
#pragma unroll
        for (int ix = 0; ix < nX; ++ix) {
            const int ky = kyA[iy], kx = kxA[ix];
            float& a = (dyA[iy] == 0) ? ((dxA[ix] == 0) ? a00 : a01)
                                      : ((dxA[ix] == 0) ? a10 : a11);
#pragma unroll
            for (int ic = 0; ic < 8; ++ic)
                a = fmaf(bf2f(h0[ic]), w2[ic * 16 + ky * 4 + kx], a);
#pragma unroll
            for (int ic = 0; ic < 8; ++ic)
                a = fmaf(bf2f(h1[ic]), w2[(ic + 8) * 16 + ky * 4 + kx], a);
        }
    }
}

__global__ __launch_bounds__(256) void tconv2_quad_k(const unsigned short* __restrict__ f1b,
                                                     const float* __restrict__ w2, const float* __restrict__ b2,
                                                     float* __restrict__ out) {
    int idx = blockIdx.x * 256 + threadIdx.x;   // 64 img * 128*128 quads
    int v = idx & 127;
    int u = (idx >> 7) & 127;
    int b = idx >> 14;
    const unsigned short* fb = f1b + (size_t)b * 262144;
    float b2s = b2[0];
    float a00 = b2s, a01 = b2s, a10 = b2s, a11 = b2s;

#define QC(RY, RX) { int jy = u + (RY), jx = v + (RX); \
    if (jy >= 0 && jy < 128 && jx >= 0 && jx < 128) \
        quad_contrib<RY, RX>(fb + ((size_t)(jy * 128 + jx) << 4), w2, a00, a01, a10, a11); }
    QC(-1, -1) QC(-1, 0) QC(-1, 1)
    QC( 0, -1) QC( 0, 0) QC( 0, 1)
    QC( 1, -1) QC( 1, 0) QC( 1, 1)
#undef QC

    float* o = out + (size_t)b * 65536 + (2 * u) * 256 + 2 * v;
    float2 r0; r0.x = a00; r0.y = a01;
    float2 r1; r1.x = a10; r1.y = a11;
    *(float2*)o         = r0;
    *(float2*)(o + 256) = r1;
}

extern "C" void kernel_launch(void* const* d_in, const int* in_sizes, int n_in,
                              void* d_out, int out_size, void* d_ws, size_t ws_size,
                              hipStream_t stream) {
    const float* x    = (const float*)d_in[0];
    const float* c1w  = (const float*)d_in[1];
    const float* c1b  = (const float*)d_in[2];
    const float* c2w  = (const float*)d_in[3];
    const float* c2b  = (const float*)d_in[4];
    const float* er1w = (const float*)d_in[5];
    const float* er1b = (const float*)d_in[6];
    const float* er2w = (const float*)d_in[7];
    const float* er2b = (const float*)d_in[8];
    const float* cb   = (const float*)d_in[9];
    const float* dr1w = (const float*)d_in[10];
    const float* dr1b = (const float*)d_in[11];
    const float* dr2w = (const float*)d_in[12];
    const float* dr2b = (const float*)d_in[13];
    const float* t1w  = (const float*)d_in[14];
    const float* t1b  = (const float*)d_in[15];
    const float* t2w  = (const float*)d_in[16];
    const float* t2b  = (const float*)d_in[17];

    char* W = (char*)d_ws;                       // 256 MiB
    const size_t MB = 1024 * 1024;
    unsigned short* f1h = (unsigned short*)(W + 0);          // conv1 hi parity-plane, 32 MiB
    unsigned short* f1l = (unsigned short*)(W + 32 * MB);    // conv1 lo parity-plane
    unsigned short* c2h = (unsigned short*)(W + 64 * MB);    // conv2 hi (64,64,64,16) ch-last
    unsigned short* c2l = (unsigned short*)(W + 80 * MB);    // conv2 lo
    unsigned short* e1h = (unsigned short*)(W + 96 * MB);    // er1 hi ch-last
    unsigned short* e1l = (unsigned short*)(W + 112 * MB);   // er1 lo
    float*          e2f = (float*)         (W + 128 * MB);   // er2 fp32 NCHW (VQ input)
    unsigned short* qc  = (unsigned short*)(W + 152 * MB);   // quantized bf16 ch-last
    unsigned short* d1o = (unsigned short*)(W + 168 * MB);   // dr1 out ch-last bf16
    unsigned short* d2o = (unsigned short*)(W + 184 * MB);   // dr2 out ch-last bf16
    unsigned short* t1o = (unsigned short*)(W + 200 * MB);   // tconv1 out (64,128,128,16) bf16

    float* out     = (float*)d_out;
    float* idx_out = out + 4194304;

    conv1_k      <<<4096, 256, 0, stream>>>(x, c1w, c1b, f1h, f1l);
    conv2_mfma_k <<<2048, 256, 0, stream>>>(f1h, f1l, c2w, c2b, c2h, c2l);
    er_mfma_k<0> <<<1024, 256, 0, stream>>>(c2h, c2l, er1w, er1b, e1h, e1l, nullptr);     // er1
    er_mfma_k<1> <<<1024, 256, 0, stream>>>(e1h, e1l, er2w, er2b, nullptr, nullptr, e2f); // er2
    vq_k         <<<1024, 256, 0, stream>>>(e2f, cb, qc, idx_out);    // argmin exact + ch-last q
    res_mfma_k   <<<1024, 256, 0, stream>>>(qc, dr1w, dr1b, d1o);     // dr1 (bf16 MFMA)
    res_mfma_k   <<<1024, 256, 0, stream>>>(d1o, dr2w, dr2b, d2o);    // dr2 (bf16 MFMA)
    tconv1_mfma_k<<<2048, 256, 0, stream>>>(d2o, t1w, t1b, t1o);
    tconv2_quad_k<<<4096, 256, 0, stream>>>(t1o, t2w, t2b, out);
}